// Round 4
// baseline (269.965 us; speedup 1.0000x reference)
//
#include <hip/hip_runtime.h>
#include <stdint.h>

// Fused MLP decode, MFMA f16. Wave = 64 points (4 sub-tiles of 16), 1 wave/block.
// NO barriers: all LDS hazards are intra-wave and the DS pipe is in-order.
// L0 transposed (W^T·X^T) -> packed-f16 LDS stores; L1 untransposed with b1
// folded into the MFMA C-init; 64->1 output layer as in-register dot + DPP
// row reduction; one fully-coalesced 256B store per group.

typedef _Float16 half8 __attribute__((ext_vector_type(8)));
typedef _Float16 half4v __attribute__((ext_vector_type(4)));
typedef float f32x4 __attribute__((ext_vector_type(4)));

#define LOG2E 1.44269504088896340736f
#define BASE_LOGIT -0.84729786038720367f   // log(0.3/0.7)
#define CSANMAX 28700.0f
#define IC_VAL 8610.0f                     // 0.3 * 28700

__device__ __forceinline__ float fast_exp2(float x) { return __builtin_amdgcn_exp2f(x); }
__device__ __forceinline__ float fast_rcp(float x)  { return __builtin_amdgcn_rcpf(x); }
__device__ __forceinline__ float sigf(float x)  { return fast_rcp(1.0f + fast_exp2(-LOG2E * x)); }
__device__ __forceinline__ float siluf(float x) { return x * sigf(x); }

template <int CTRL>
__device__ __forceinline__ float dpp_radd(float x) {
  int yi = __builtin_amdgcn_update_dpp(0, __builtin_bit_cast(int, x), CTRL, 0xF, 0xF, false);
  return x + __builtin_bit_cast(float, yi);
}
// full sum across the 16 lanes of a DPP row (our q-group); result in all 16 lanes
__device__ __forceinline__ float row_sum16(float x) {
  x = dpp_radd<0xB1>(x);    // quad_perm [1,0,3,2]  : + lane^1
  x = dpp_radd<0x4E>(x);    // quad_perm [2,3,0,1]  : + lane^2
  x = dpp_radd<0x141>(x);   // row_half_mirror      : pair quads
  x = dpp_radd<0x140>(x);   // row_mirror           : pair octets
  return x;
}

__global__ __launch_bounds__(64, 4) void mlp_kernel(
    const int* __restrict__ tix, const float* __restrict__ rho,
    const float* __restrict__ emb, const float* __restrict__ W0,
    const float* __restrict__ b0, const float* __restrict__ W1,
    const float* __restrict__ b1, const float* __restrict__ Wout,
    const float* __restrict__ bout, float* __restrict__ out, int ngroups)
{
  // F: features for 64 points, stride 40 halfs (80B). H: per-sub-tile h1,
  // double-buffered, stride 72 halfs (144B). Total 9728 B -> 16 blocks/CU.
  __shared__ __align__(16) _Float16 F[64][40];
  __shared__ __align__(16) _Float16 H[2][16][72];

  const int lane = threadIdx.x;  // 0..63
  const int m    = lane & 15;
  const int q    = lane >> 4;

  // ---- one-time: weight fragments (72 persistent VGPRs) ----
  // content B[k=s*32+q*8+j][n=t*16+m]; used as A-op for L0 (=> W^T), B-op for L1.
  half8 B0f[4][2], B1f[4][2];
#pragma unroll
  for (int t = 0; t < 4; ++t) {
#pragma unroll
    for (int s = 0; s < 2; ++s) {
      half8 f0, f1;
#pragma unroll
      for (int j = 0; j < 8; ++j) {
        const int k = s * 32 + q * 8 + j;
        const int n = t * 16 + m;
        // pad K 49->64; fold b0 into k==49 (feature there is 1.0)
        const float v0 = (k < 49) ? W0[k * 64 + n] : ((k == 49) ? b0[n] : 0.0f);
        f0[j] = (_Float16)v0;
        f1[j] = (_Float16)W1[k * 64 + n];
      }
      B0f[t][s] = f0;
      B1f[t][s] = f1;
    }
  }
  float b1n[4], woutm[4];
#pragma unroll
  for (int t = 0; t < 4; ++t) {
    b1n[t]   = b1[t * 16 + m];
    woutm[t] = Wout[t * 16 + m];
  }
  const float boutBL = bout[0] + BASE_LOGIT;

  // one-time: constant feature cols. col 17 (k=49) = 1.0 bias slot; 18..31 = 0.
  {
    half8 zc = (half8)(_Float16)0.0f;
    half8 c16 = zc; c16[1] = (_Float16)1.0f;  // col16 placeholder (s8, per-group), col17=1
    *(half8*)&F[lane][16] = c16;
    *(half8*)&F[lane][24] = zc;
  }

  const f32x4 z = {0.0f, 0.0f, 0.0f, 0.0f};

  for (int g = blockIdx.x; g < ngroups; g += gridDim.x) {
    const int gbase = g * 64;

    // ---- P1: per-lane point loads + Fourier features (Chebyshev) ----
    const int   tiL = tix[gbase + lane];   // for the final epilogue (own point)
    const float rh  = rho[gbase + lane];
    const float rev = 0.5f * rh;           // v_sin/v_cos take revolutions
    const float c1 = __builtin_amdgcn_cosf(rev);
    const float s1 = __builtin_amdgcn_sinf(rev);
    float cs[8], sn[8];
    cs[0] = c1; sn[0] = s1;
    {
      float cm2 = 1.0f, cm1 = c1, sm2 = 0.0f, sm1 = s1;
      const float tc = 2.0f * c1;
#pragma unroll
      for (int k = 1; k < 8; ++k) {
        const float ck = tc * cm1 - cm2;
        const float sk = tc * sm1 - sm2;
        cs[k] = ck; sn[k] = sk;
        cm2 = cm1; cm1 = ck; sm2 = sm1; sm1 = sk;
      }
    }
    half8 h0, h1;
    h0[0] = (_Float16)rh;
#pragma unroll
    for (int k = 0; k < 7; ++k) h0[1 + k] = (_Float16)cs[k];
    h1[0] = (_Float16)cs[7];
#pragma unroll
    for (int k = 0; k < 7; ++k) h1[1 + k] = (_Float16)sn[k];
    *(half8*)&F[lane][0] = h0;
    *(half8*)&F[lane][8] = h1;
    F[lane][16] = (_Float16)sn[7];
    // no barrier: same-wave DS ops are in-order

    float dcar = 0.0f;  // carried raw output dot for point gbase+lane

#pragma unroll
    for (int st = 0; st < 4; ++st) {
      _Float16 (*Hb)[72] = H[st & 1];

      // ---- L0 (transposed): D = W0^T · X^T ----
      // B-op s0: emb gather — lane(m,q) holds emb[point st*16+m][q*8..+8]
      const int tim  = tix[gbase + st * 16 + m];        // broadcast x4 lanes, L1-hit
      const int idxm = min(max(tim - 1, 0), 510);
      const float* erow = emb + (size_t)idxm * 32 + q * 8;
      const f32x4 e0 = *(const f32x4*)erow;
      const f32x4 e1 = *(const f32x4*)(erow + 4);
      half8 X0;
#pragma unroll
      for (int j = 0; j < 4; ++j) {
        X0[j]     = (_Float16)e0[j];
        X0[4 + j] = (_Float16)e1[j];
      }
      // B-op s1: features of point st*16+m
      const half8 X1 = *(const half8*)&F[st * 16 + m][q * 8];

      f32x4 acc[4];
#pragma unroll
      for (int t = 0; t < 4; ++t) {
        f32x4 a = __builtin_amdgcn_mfma_f32_16x16x32_f16(B0f[t][0], X0, z, 0, 0, 0);
        a = __builtin_amdgcn_mfma_f32_16x16x32_f16(B0f[t][1], X1, a, 0, 0, 0);
        acc[t] = a;
      }
      // epilogue: lane(m,q) reg r = preact[hidden=t*16+q*4+r][point=st*16+m]
#pragma unroll
      for (int t = 0; t < 4; ++t) {
        half4v hh;
#pragma unroll
        for (int r = 0; r < 4; ++r) hh[r] = (_Float16)siluf(acc[t][r]);
        *(half4v*)&Hb[m][t * 16 + q * 4] = hh;
      }

      // ---- L1 (untransposed): D = h1 · W1 + b1 (b1 via C-init) ----
      const half8 Y0 = *(const half8*)&Hb[m][q * 8];        // in-order DS: RAW safe
      const half8 Y1 = *(const half8*)&Hb[m][32 + q * 8];
#pragma unroll
      for (int t = 0; t < 4; ++t) {
        const f32x4 binit = {b1n[t], b1n[t], b1n[t], b1n[t]};
        f32x4 a = __builtin_amdgcn_mfma_f32_16x16x32_f16(Y0, B1f[t][0], binit, 0, 0, 0);
        a = __builtin_amdgcn_mfma_f32_16x16x32_f16(Y1, B1f[t][1], a, 0, 0, 0);
        acc[t] = a;
      }
      // C[point=q*4+r][hidden=t*16+m]: fuse silu + Wout dot in regs
      float dot0 = 0.0f, dot1 = 0.0f, dot2 = 0.0f, dot3 = 0.0f;
#pragma unroll
      for (int t = 0; t < 4; ++t) {
        dot0 = fmaf(siluf(acc[t][0]), woutm[t], dot0);
        dot1 = fmaf(siluf(acc[t][1]), woutm[t], dot1);
        dot2 = fmaf(siluf(acc[t][2]), woutm[t], dot2);
        dot3 = fmaf(siluf(acc[t][3]), woutm[t], dot3);
      }
      // reduce over the 16 m-lanes of each q-row (DPP, VALU pipe)
      dot0 = row_sum16(dot0);
      dot1 = row_sum16(dot1);
      dot2 = row_sum16(dot2);
      dot3 = row_sum16(dot3);
      // route to owner lanes: lane L wants point st*16 + m (kept only when q==st).
      // value for point st*16+m lives as dots[m&3] in row (m>>2).
      const float dsel = (m & 2) ? ((m & 1) ? dot3 : dot2) : ((m & 1) ? dot1 : dot0);
      const float dg = __shfl(dsel, (m >> 2) * 16 + (m & 3), 64);
      dcar = (q == st) ? dg : dcar;
    }

    // ---- epilogue: one coalesced 256B store per group ----
    const float theta = sigf(dcar + boutBL);
    out[gbase + lane] = (tiL == 0) ? IC_VAL : theta * CSANMAX;
  }
}

extern "C" void kernel_launch(void* const* d_in, const int* in_sizes, int n_in,
                              void* d_out, int out_size, void* d_ws, size_t ws_size,
                              hipStream_t stream) {
  const int*   tix  = (const int*)d_in[0];
  const float* rho  = (const float*)d_in[1];
  const float* emb  = (const float*)d_in[2];
  const float* W0   = (const float*)d_in[3];
  const float* b0   = (const float*)d_in[4];
  const float* W1   = (const float*)d_in[5];
  const float* b1   = (const float*)d_in[6];
  const float* Wout = (const float*)d_in[7];
  const float* bout = (const float*)d_in[8];
  float* outp = (float*)d_out;

  const int n       = in_sizes[0];   // 2,000,000 (divisible by 64)
  const int ngroups = n / 64;        // 31,250 groups of 64 points

  int grid = 4096;                   // 16 single-wave blocks/CU (LDS+wg cap)
  if (grid > ngroups) grid = ngroups;
  mlp_kernel<<<dim3(grid), dim3(64), 0, stream>>>(
      tix, rho, emb, W0, b0, W1, b1, Wout, bout, outp, ngroups);
}

// Round 5
// 200.572 us; speedup vs baseline: 1.3460x; 1.3460x over previous
//
#include <hip/hip_runtime.h>
#include <stdint.h>

// Fused MLP decode, MFMA f16. Wave = 64 points (4 sub-tiles of 16), 1 wave/block.
// NO barriers: all LDS hazards are intra-wave and the DS pipe is in-order.
// L0 transposed (W^T·X^T) -> packed-f16 LDS stores; L1 untransposed with b1
// folded into the MFMA C-init; 64->1 output layer as in-register dot + DPP
// row reduction; one fully-coalesced 256B store per group.
// NOTE: __launch_bounds__(64) ONLY — adding a min-waves/EU hint (",4") drove
// the allocator to a 64-VGPR target and produced ~600 MB/dispatch of scratch
// spill traffic (R3/R4). This kernel needs ~110 VGPRs (72 persistent weights).

typedef _Float16 half8 __attribute__((ext_vector_type(8)));
typedef _Float16 half4v __attribute__((ext_vector_type(4)));
typedef float f32x4 __attribute__((ext_vector_type(4)));

#define LOG2E 1.44269504088896340736f
#define BASE_LOGIT -0.84729786038720367f   // log(0.3/0.7)
#define CSANMAX 28700.0f
#define IC_VAL 8610.0f                     // 0.3 * 28700

__device__ __forceinline__ float fast_exp2(float x) { return __builtin_amdgcn_exp2f(x); }
__device__ __forceinline__ float fast_rcp(float x)  { return __builtin_amdgcn_rcpf(x); }
__device__ __forceinline__ float sigf(float x)  { return fast_rcp(1.0f + fast_exp2(-LOG2E * x)); }
__device__ __forceinline__ float siluf(float x) { return x * sigf(x); }

template <int CTRL>
__device__ __forceinline__ float dpp_radd(float x) {
  int yi = __builtin_amdgcn_update_dpp(0, __builtin_bit_cast(int, x), CTRL, 0xF, 0xF, false);
  return x + __builtin_bit_cast(float, yi);
}
// full sum across the 16 lanes of a DPP row (our q-group); result in all 16 lanes
__device__ __forceinline__ float row_sum16(float x) {
  x = dpp_radd<0xB1>(x);    // quad_perm [1,0,3,2]  : + lane^1
  x = dpp_radd<0x4E>(x);    // quad_perm [2,3,0,1]  : + lane^2
  x = dpp_radd<0x141>(x);   // row_half_mirror      : pair quads
  x = dpp_radd<0x140>(x);   // row_mirror           : pair octets
  return x;
}

__global__ __launch_bounds__(64) void mlp_kernel(
    const int* __restrict__ tix, const float* __restrict__ rho,
    const float* __restrict__ emb, const float* __restrict__ W0,
    const float* __restrict__ b0, const float* __restrict__ W1,
    const float* __restrict__ b1, const float* __restrict__ Wout,
    const float* __restrict__ bout, float* __restrict__ out, int ngroups)
{
  // F: features for 64 points, stride 40 halfs (80B). H: per-sub-tile h1,
  // double-buffered, stride 72 halfs (144B). Total 9728 B.
  __shared__ __align__(16) _Float16 F[64][40];
  __shared__ __align__(16) _Float16 H[2][16][72];

  const int lane = threadIdx.x;  // 0..63
  const int m    = lane & 15;
  const int q    = lane >> 4;

  // ---- one-time: weight fragments (72 persistent VGPRs) ----
  // content B[k=s*32+q*8+j][n=t*16+m]; used as A-op for L0 (=> W^T), B-op for L1.
  half8 B0f[4][2], B1f[4][2];
#pragma unroll
  for (int t = 0; t < 4; ++t) {
#pragma unroll
    for (int s = 0; s < 2; ++s) {
      half8 f0, f1;
#pragma unroll
      for (int j = 0; j < 8; ++j) {
        const int k = s * 32 + q * 8 + j;
        const int n = t * 16 + m;
        // pad K 49->64; fold b0 into k==49 (feature there is 1.0)
        const float v0 = (k < 49) ? W0[k * 64 + n] : ((k == 49) ? b0[n] : 0.0f);
        f0[j] = (_Float16)v0;
        f1[j] = (_Float16)W1[k * 64 + n];
      }
      B0f[t][s] = f0;
      B1f[t][s] = f1;
    }
  }
  float b1n[4], woutm[4];
#pragma unroll
  for (int t = 0; t < 4; ++t) {
    b1n[t]   = b1[t * 16 + m];
    woutm[t] = Wout[t * 16 + m];
  }
  const float boutBL = bout[0] + BASE_LOGIT;

  // one-time: constant feature cols. col 17 (k=49) = 1.0 bias slot; 18..31 = 0.
  {
    half8 zc = (half8)(_Float16)0.0f;
    half8 c16 = zc; c16[1] = (_Float16)1.0f;  // col16 placeholder (s8, per-group), col17=1
    *(half8*)&F[lane][16] = c16;
    *(half8*)&F[lane][24] = zc;
  }

  const f32x4 z = {0.0f, 0.0f, 0.0f, 0.0f};

  for (int g = blockIdx.x; g < ngroups; g += gridDim.x) {
    const int gbase = g * 64;

    // ---- P1: per-lane point loads + Fourier features (Chebyshev) ----
    const int   tiL = tix[gbase + lane];   // for the final epilogue (own point)
    const float rh  = rho[gbase + lane];
    const float rev = 0.5f * rh;           // v_sin/v_cos take revolutions
    const float c1 = __builtin_amdgcn_cosf(rev);
    const float s1 = __builtin_amdgcn_sinf(rev);
    // convert inside the recurrence: keeps only 4 floats live
    half8 h0, h1;
    h0[0] = (_Float16)rh;
    h0[1] = (_Float16)c1;
    h1[1] = (_Float16)s1;
    {
      float cm2 = 1.0f, cm1 = c1, sm2 = 0.0f, sm1 = s1;
      const float tc = 2.0f * c1;
#pragma unroll
      for (int k = 2; k <= 8; ++k) {
        const float ck = tc * cm1 - cm2;
        const float sk = tc * sm1 - sm2;
        if (k < 8) { h0[k] = (_Float16)ck; h1[k] = (_Float16)sk; }
        else       { h1[0] = (_Float16)ck; /* c8 */ }
        if (k == 8) F[lane][16] = (_Float16)sk;  // s8 scalar slot
        cm2 = cm1; cm1 = ck; sm2 = sm1; sm1 = sk;
      }
    }
    // F row layout: [rho, c1..c7 | c8, s1..s7 | s8, 1.0, 0...]
    *(half8*)&F[lane][0] = h0;
    *(half8*)&F[lane][8] = h1;
    // no barrier: same-wave DS ops are in-order

    float dcar = 0.0f;  // carried raw output dot for point gbase+lane

#pragma unroll
    for (int st = 0; st < 4; ++st) {
      _Float16 (*Hb)[72] = H[st & 1];

      // ---- L0 (transposed): D = W0^T · X^T ----
      // B-op s0: emb gather — lane(m,q) holds emb[point st*16+m][q*8..+8]
      const int tim  = tix[gbase + st * 16 + m];        // broadcast x4 lanes, L1-hit
      const int idxm = min(max(tim - 1, 0), 510);
      const float* erow = emb + (size_t)idxm * 32 + q * 8;
      const f32x4 e0 = *(const f32x4*)erow;
      const f32x4 e1 = *(const f32x4*)(erow + 4);
      half8 X0;
#pragma unroll
      for (int j = 0; j < 4; ++j) {
        X0[j]     = (_Float16)e0[j];
        X0[4 + j] = (_Float16)e1[j];
      }
      // B-op s1: features of point st*16+m
      const half8 X1 = *(const half8*)&F[st * 16 + m][q * 8];

      f32x4 acc[4];
#pragma unroll
      for (int t = 0; t < 4; ++t) {
        f32x4 a = __builtin_amdgcn_mfma_f32_16x16x32_f16(B0f[t][0], X0, z, 0, 0, 0);
        a = __builtin_amdgcn_mfma_f32_16x16x32_f16(B0f[t][1], X1, a, 0, 0, 0);
        acc[t] = a;
      }
      // epilogue: lane(m,q) reg r = preact[hidden=t*16+q*4+r][point=st*16+m]
#pragma unroll
      for (int t = 0; t < 4; ++t) {
        half4v hh;
#pragma unroll
        for (int r = 0; r < 4; ++r) hh[r] = (_Float16)siluf(acc[t][r]);
        *(half4v*)&Hb[m][t * 16 + q * 4] = hh;
      }

      // ---- L1 (untransposed): D = h1 · W1 + b1 (b1 via C-init) ----
      const half8 Y0 = *(const half8*)&Hb[m][q * 8];        // in-order DS: RAW safe
      const half8 Y1 = *(const half8*)&Hb[m][32 + q * 8];
#pragma unroll
      for (int t = 0; t < 4; ++t) {
        const f32x4 binit = {b1n[t], b1n[t], b1n[t], b1n[t]};
        f32x4 a = __builtin_amdgcn_mfma_f32_16x16x32_f16(Y0, B1f[t][0], binit, 0, 0, 0);
        a = __builtin_amdgcn_mfma_f32_16x16x32_f16(Y1, B1f[t][1], a, 0, 0, 0);
        acc[t] = a;
      }
      // C[point=q*4+r][hidden=t*16+m]: fuse silu + Wout dot in regs
      float dot0 = 0.0f, dot1 = 0.0f, dot2 = 0.0f, dot3 = 0.0f;
#pragma unroll
      for (int t = 0; t < 4; ++t) {
        dot0 = fmaf(siluf(acc[t][0]), woutm[t], dot0);
        dot1 = fmaf(siluf(acc[t][1]), woutm[t], dot1);
        dot2 = fmaf(siluf(acc[t][2]), woutm[t], dot2);
        dot3 = fmaf(siluf(acc[t][3]), woutm[t], dot3);
      }
      // reduce over the 16 m-lanes of each q-row (DPP, VALU pipe)
      dot0 = row_sum16(dot0);
      dot1 = row_sum16(dot1);
      dot2 = row_sum16(dot2);
      dot3 = row_sum16(dot3);
      // route to owner lanes: lane L wants point st*16 + m (kept only when q==st).
      // value for point st*16+m lives as dots[m&3] in row (m>>2).
      const float dsel = (m & 2) ? ((m & 1) ? dot3 : dot2) : ((m & 1) ? dot1 : dot0);
      const float dg = __shfl(dsel, (m >> 2) * 16 + (m & 3), 64);
      dcar = (q == st) ? dg : dcar;
    }

    // ---- epilogue: one coalesced 256B store per group ----
    const float theta = sigf(dcar + boutBL);
    out[gbase + lane] = (tiL == 0) ? IC_VAL : theta * CSANMAX;
  }
}

extern "C" void kernel_launch(void* const* d_in, const int* in_sizes, int n_in,
                              void* d_out, int out_size, void* d_ws, size_t ws_size,
                              hipStream_t stream) {
  const int*   tix  = (const int*)d_in[0];
  const float* rho  = (const float*)d_in[1];
  const float* emb  = (const float*)d_in[2];
  const float* W0   = (const float*)d_in[3];
  const float* b0   = (const float*)d_in[4];
  const float* W1   = (const float*)d_in[5];
  const float* b1   = (const float*)d_in[6];
  const float* Wout = (const float*)d_in[7];
  const float* bout = (const float*)d_in[8];
  float* outp = (float*)d_out;

  const int n       = in_sizes[0];   // 2,000,000 (divisible by 64)
  const int ngroups = n / 64;        // 31,250 groups of 64 points

  int grid = 4096;                   // 1 wave/block; grid-stride over groups
  if (grid > ngroups) grid = ngroups;
  mlp_kernel<<<dim3(grid), dim3(64), 0, stream>>>(
      tix, rho, emb, W0, b0, W1, b1, Wout, bout, outp, ngroups);
}

// Round 7
// 174.720 us; speedup vs baseline: 1.5451x; 1.1480x over previous
//
#include <hip/hip_runtime.h>
#include <stdint.h>

// Fused MLP decode, MFMA f16. Wave = 64 points (4 sub-tiles of 16).
// 2-wave workgroups, ZERO barriers: every LDS region is wave-private and the
// DS pipe is in-order within a wave. L0 transposed (W^T·X^T) -> packed-f16
// LDS stores; L1 untransposed with b1 via MFMA C-init; 64->1 layer as
// in-register dot + DPP row reduction; one coalesced 256B store per group.
// NOTE: __launch_bounds__ has NO min-waves arg — ",4" forced a 64-VGPR
// target and ~600MB/dispatch scratch spills (R3/R4). Needs ~110 VGPRs.

typedef _Float16 half8  __attribute__((ext_vector_type(8)));
typedef _Float16 half4v __attribute__((ext_vector_type(4)));
typedef _Float16 half2v __attribute__((ext_vector_type(2)));
typedef float f32x4 __attribute__((ext_vector_type(4)));

#define LOG2E 1.44269504088896340736f
#define BASE_LOGIT -0.84729786038720367f   // log(0.3/0.7)
#define CSANMAX 28700.0f
#define IC_VAL 8610.0f                     // 0.3 * 28700

__device__ __forceinline__ float fast_exp2(float x) { return __builtin_amdgcn_exp2f(x); }
__device__ __forceinline__ float fast_rcp(float x)  { return __builtin_amdgcn_rcpf(x); }
__device__ __forceinline__ float sigf(float x)  { return fast_rcp(1.0f + fast_exp2(-LOG2E * x)); }
__device__ __forceinline__ float siluf(float x) { return x * sigf(x); }
__device__ __forceinline__ half2v pkh(float a, float b) {
  return __builtin_bit_cast(half2v, __builtin_amdgcn_cvt_pkrtz(a, b));
}

union H8 { half8 v8; half2v v2[4]; };
union H4 { half4v v4; half2v v2[2]; };

template <int CTRL>
__device__ __forceinline__ float dpp_radd(float x) {
  int yi = __builtin_amdgcn_update_dpp(0, __builtin_bit_cast(int, x), CTRL, 0xF, 0xF, false);
  return x + __builtin_bit_cast(float, yi);
}
// sum across the 16 lanes of a DPP row (our q-group); result in all 16 lanes
__device__ __forceinline__ float row_sum16(float x) {
  x = dpp_radd<0xB1>(x);    // quad_perm [1,0,3,2]
  x = dpp_radd<0x4E>(x);    // quad_perm [2,3,0,1]
  x = dpp_radd<0x141>(x);   // row_half_mirror
  x = dpp_radd<0x140>(x);   // row_mirror
  return x;
}

__global__ __launch_bounds__(128) void mlp_kernel(
    const int* __restrict__ tix, const float* __restrict__ rho,
    const float* __restrict__ emb, const float* __restrict__ W0,
    const float* __restrict__ b0, const float* __restrict__ W1,
    const float* __restrict__ b1, const float* __restrict__ Wout,
    const float* __restrict__ bout, float* __restrict__ out, int ngroups)
{
  // per-wave regions: F stride 40 halfs (80B), H stride 72 halfs (144B).
  __shared__ __align__(16) _Float16 ldsF[2][64][40];
  __shared__ __align__(16) _Float16 ldsH[2][2][16][72];

  const int tid  = threadIdx.x;
  const int wid  = tid >> 6;
  const int lane = tid & 63;
  const int m    = lane & 15;
  const int q    = lane >> 4;

  _Float16 (*F)[40]      = ldsF[wid];
  _Float16 (*Hd)[16][72] = ldsH[wid];

  // ---- one-time: weight fragments (72 persistent VGPRs) ----
  // content B[k=s*32+q*8+j][n=t*16+m]; A-op for L0 (=> W^T), B-op for L1.
  half8 B0f[4][2], B1f[4][2];
#pragma unroll
  for (int t = 0; t < 4; ++t) {
#pragma unroll
    for (int s = 0; s < 2; ++s) {
      half8 f0, f1;
#pragma unroll
      for (int j = 0; j < 8; ++j) {
        const int k = s * 32 + q * 8 + j;
        const int n = t * 16 + m;
        // pad K 49->64; fold b0 into k==49 (feature there is 1.0)
        const float v0 = (k < 49) ? W0[k * 64 + n] : ((k == 49) ? b0[n] : 0.0f);
        f0[j] = (_Float16)v0;
        f1[j] = (_Float16)W1[k * 64 + n];
      }
      B0f[t][s] = f0;
      B1f[t][s] = f1;
    }
  }
  float b1n[4], woutm[4];
#pragma unroll
  for (int t = 0; t < 4; ++t) {
    b1n[t]   = b1[t * 16 + m];
    woutm[t] = Wout[t * 16 + m];
  }
  const float boutBL = bout[0] + BASE_LOGIT;

  // one-time: zero the constant K-pad cols 18..31 (16..17 rewritten per group)
  {
    half8 zc = (half8)(_Float16)0.0f;
    *(half8*)&F[lane][16] = zc;
    *(half8*)&F[lane][24] = zc;
  }

  const f32x4 z = {0.0f, 0.0f, 0.0f, 0.0f};
  const int gwaves = gridDim.x * 2;

  for (int g = blockIdx.x * 2 + wid; g < ngroups; g += gwaves) {
    const int gbase = g * 64;

    // ---- P1: per-lane point loads + Fourier features (Chebyshev) ----
    const int   tiL = tix[gbase + lane];
    const float rh  = rho[gbase + lane];
    const float rev = 0.5f * rh;           // v_sin/v_cos take revolutions
    const float c1 = __builtin_amdgcn_cosf(rev);
    const float s1 = __builtin_amdgcn_sinf(rev);
    float cs[8], sn[8];
    cs[0] = c1; sn[0] = s1;
    {
      float cm2 = 1.0f, cm1 = c1, sm2 = 0.0f, sm1 = s1;
      const float tc = 2.0f * c1;
#pragma unroll
      for (int k = 1; k < 8; ++k) {
        const float ck = tc * cm1 - cm2;
        const float sk = tc * sm1 - sm2;
        cs[k] = ck; sn[k] = sk;
        cm2 = cm1; cm1 = ck; sm2 = sm1; sm1 = sk;
      }
    }
    // F row: [rho, c1..c7 | c8, s1..s7 | s8, 1.0, 0 x14 | pad]
    H8 h0, h1;
    h0.v2[0] = pkh(rh,    cs[0]); h0.v2[1] = pkh(cs[1], cs[2]);
    h0.v2[2] = pkh(cs[3], cs[4]); h0.v2[3] = pkh(cs[5], cs[6]);
    h1.v2[0] = pkh(cs[7], sn[0]); h1.v2[1] = pkh(sn[1], sn[2]);
    h1.v2[2] = pkh(sn[3], sn[4]); h1.v2[3] = pkh(sn[5], sn[6]);
    *(half8*)&F[lane][0] = h0.v8;
    *(half8*)&F[lane][8] = h1.v8;
    *(half2v*)&F[lane][16] = pkh(sn[7], 1.0f);
    // no barrier: same-wave DS ops are in-order

    float dcar = 0.0f;  // carried raw output dot for point gbase+lane

#pragma unroll
    for (int st = 0; st < 4; ++st) {
      _Float16 (*Hb)[72] = Hd[st & 1];

      // ---- L0 (transposed): D = W0^T · X^T ----
      // B-op s0: emb gather — lane(m,q) holds emb[point st*16+m][q*8..+8]
      const int tim  = __shfl(tiL, st * 16 + m, 64);
      const int idxm = min(max(tim - 1, 0), 510);
      const float* erow = emb + (size_t)idxm * 32 + q * 8;
      const f32x4 e0 = *(const f32x4*)erow;
      const f32x4 e1 = *(const f32x4*)(erow + 4);
      H8 X0;
      X0.v2[0] = pkh(e0[0], e0[1]); X0.v2[1] = pkh(e0[2], e0[3]);
      X0.v2[2] = pkh(e1[0], e1[1]); X0.v2[3] = pkh(e1[2], e1[3]);
      // B-op s1: features of point st*16+m
      const half8 X1 = *(const half8*)&F[st * 16 + m][q * 8];

      f32x4 acc[4];
#pragma unroll
      for (int t = 0; t < 4; ++t) {
        f32x4 a = __builtin_amdgcn_mfma_f32_16x16x32_f16(B0f[t][0], X0.v8, z, 0, 0, 0);
        a = __builtin_amdgcn_mfma_f32_16x16x32_f16(B0f[t][1], X1, a, 0, 0, 0);
        acc[t] = a;
      }
      // epilogue: lane(m,q) reg r = preact[hidden=t*16+q*4+r][point=st*16+m]
#pragma unroll
      for (int t = 0; t < 4; ++t) {
        H4 hh;
        hh.v2[0] = pkh(siluf(acc[t][0]), siluf(acc[t][1]));
        hh.v2[1] = pkh(siluf(acc[t][2]), siluf(acc[t][3]));
        *(half4v*)&Hb[m][t * 16 + q * 4] = hh.v4;
      }

      // ---- L1 (untransposed): D = h1 · W1 + b1 (b1 via C-init) ----
      const half8 Y0 = *(const half8*)&Hb[m][q * 8];        // in-order DS: RAW safe
      const half8 Y1 = *(const half8*)&Hb[m][32 + q * 8];
#pragma unroll
      for (int t = 0; t < 4; ++t) {
        const f32x4 binit = {b1n[t], b1n[t], b1n[t], b1n[t]};
        f32x4 a = __builtin_amdgcn_mfma_f32_16x16x32_f16(Y0, B1f[t][0], binit, 0, 0, 0);
        a = __builtin_amdgcn_mfma_f32_16x16x32_f16(Y1, B1f[t][1], a, 0, 0, 0);
        acc[t] = a;
      }
      // C[point=q*4+r][hidden=t*16+m]: fuse silu + Wout dot in regs
      float dot0 = 0.0f, dot1 = 0.0f, dot2 = 0.0f, dot3 = 0.0f;
#pragma unroll
      for (int t = 0; t < 4; ++t) {
        dot0 = fmaf(siluf(acc[t][0]), woutm[t], dot0);
        dot1 = fmaf(siluf(acc[t][1]), woutm[t], dot1);
        dot2 = fmaf(siluf(acc[t][2]), woutm[t], dot2);
        dot3 = fmaf(siluf(acc[t][3]), woutm[t], dot3);
      }
      // reduce over the 16 m-lanes of each q-row (DPP, VALU pipe)
      dot0 = row_sum16(dot0);
      dot1 = row_sum16(dot1);
      dot2 = row_sum16(dot2);
      dot3 = row_sum16(dot3);
      // route: value for point st*16+m lives as dots[m&3] in row (m>>2)
      const float dsel = (m & 2) ? ((m & 1) ? dot3 : dot2) : ((m & 1) ? dot1 : dot0);
      const float dg = __shfl(dsel, (m >> 2) * 16 + (m & 3), 64);
      dcar = (q == st) ? dg : dcar;
    }

    // ---- epilogue: one coalesced 256B store per group ----
    const float theta = sigf(dcar + boutBL);
    out[gbase + lane] = (tiL == 0) ? IC_VAL : theta * CSANMAX;
  }
}

extern "C" void kernel_launch(void* const* d_in, const int* in_sizes, int n_in,
                              void* d_out, int out_size, void* d_ws, size_t ws_size,
                              hipStream_t stream) {
  const int*   tix  = (const int*)d_in[0];
  const float* rho  = (const float*)d_in[1];
  const float* emb  = (const float*)d_in[2];
  const float* W0   = (const float*)d_in[3];
  const float* b0   = (const float*)d_in[4];
  const float* W1   = (const float*)d_in[5];
  const float* b1   = (const float*)d_in[6];
  const float* Wout = (const float*)d_in[7];
  const float* bout = (const float*)d_in[8];
  float* outp = (float*)d_out;

  const int n       = in_sizes[0];   // 2,000,000 (divisible by 64)
  const int ngroups = n / 64;        // 31,250 groups of 64 points

  int grid = 2048;                   // 2-wave blocks: 4096 waves, 8 blocks/CU
  if (grid * 2 > ngroups) grid = (ngroups + 1) / 2;
  mlp_kernel<<<dim3(grid), dim3(128), 0, stream>>>(
      tix, rho, emb, W0, b0, W1, b1, Wout, bout, outp, ngroups);
}